// Round 4
// baseline (473.572 us; speedup 1.0000x reference)
//
#include <hip/hip_runtime.h>
#include <hip/hip_bf16.h>
#include <math.h>

#define T_CONST 2048
#define D_CONST 1024
#define I_CONST 512
#define SI_CONST 1024
#define E_CONST 32
#define G_CONST 8
#define LG_CONST 4
#define KSEL 6
#define BK 32

typedef __attribute__((ext_vector_type(8))) short short8;
typedef __attribute__((ext_vector_type(4))) float floatx4;

__device__ inline unsigned pack_bf16(float a, float b) {
  __hip_bfloat162 h = __float22bfloat162_rn(float2{a, b});
  return *reinterpret_cast<unsigned*>(&h);
}

// async global->LDS, 16B per lane; LDS dest must be base + lane*16.
__device__ inline void gload16(const void* g, void* l) {
  __builtin_amdgcn_global_load_lds(
      (const __attribute__((address_space(1))) unsigned int*)g,
      (__attribute__((address_space(3))) unsigned int*)l, 16, 0, 0);
}

// ---------------- conversions ----------------
__global__ __launch_bounds__(256) void cvt_x(const float* __restrict__ in,
                                             __hip_bfloat16* __restrict__ out) {
  size_t i = ((size_t)blockIdx.x * 256 + threadIdx.x) * 4;
  float4 v = *(const float4*)&in[i];
  uint2 u{pack_bf16(v.x, v.y), pack_bf16(v.z, v.w)};
  *(uint2*)&out[i] = u;
}

__global__ __launch_bounds__(256) void cvt_rwt(const float* __restrict__ rw,
                                               float* __restrict__ rwt) {
  int i = blockIdx.x * 256 + threadIdx.x;  // 32768 total
  int d = i >> 5, e = i & 31;
  rwt[d * 32 + e] = rw[e * D_CONST + d];
}

// fp32 [K][N] row-major -> bf16 [N][K], fused over all weights.
// Register 4x4 transpose + bf16 LDS with chunk-XOR swizzle:
// logical chunk cu (8 shorts) of row n stored at cx = cu ^ ((n>>2)&7).
// Per-16-lane-group bank analysis: 2-way (free) on both phases.
__global__ __launch_bounds__(256) void transpose_all(
    const float* __restrict__ W1, const float* __restrict__ W2,
    const float* __restrict__ W3, const float* __restrict__ sw1,
    const float* __restrict__ sw2, const float* __restrict__ sw3,
    __hip_bfloat16* __restrict__ W1t, __hip_bfloat16* __restrict__ W2t,
    __hip_bfloat16* __restrict__ W3t, __hip_bfloat16* __restrict__ sw1t,
    __hip_bfloat16* __restrict__ sw2t, __hip_bfloat16* __restrict__ sw3t) {
  __shared__ short tile[64 * 64];
  int b = blockIdx.x;
  const float* in;
  __hip_bfloat16* out;
  int K, N, k0, n0;
  if (b < 8192) {  // W1 / W2 : K=1024, N=512, 128 blocks per matrix
    int local = b & 4095;
    int mat = local >> 7, rem = local & 127;
    K = 1024; N = 512;
    in = ((b < 4096) ? W1 : W2) + (size_t)mat * (1024 * 512);
    out = ((b < 4096) ? W1t : W2t) + (size_t)mat * (1024 * 512);
    n0 = (rem & 7) * 64; k0 = (rem >> 3) * 64;
  } else if (b < 12288) {  // W3 : K=512, N=1024
    int local = b - 8192;
    int mat = local >> 7, rem = local & 127;
    K = 512; N = 1024;
    in = W3 + (size_t)mat * (512 * 1024);
    out = W3t + (size_t)mat * (512 * 1024);
    n0 = (rem & 15) * 64; k0 = (rem >> 4) * 64;
  } else {  // sw1/sw2/sw3 : 1024x1024
    int local = b - 12288;
    int which = local >> 8, rem = local & 255;
    K = 1024; N = 1024;
    in = which == 0 ? sw1 : which == 1 ? sw2 : sw3;
    out = which == 0 ? sw1t : which == 1 ? sw2t : sw3t;
    n0 = (rem & 15) * 64; k0 = (rem >> 4) * 64;
  }
  const int tid = threadIdx.x;
  const int u = tid & 15, tr = tid >> 4;  // u: col group, tr: row group
  float4 v[4];
#pragma unroll
  for (int r = 0; r < 4; ++r)
    v[r] = *(const float4*)&in[(size_t)(k0 + 4 * tr + r) * N + n0 + 4 * u];
#pragma unroll
  for (int j = 0; j < 4; ++j) {
    int n = 4 * u + j;
    unsigned lo = pack_bf16(((const float*)&v[0])[j], ((const float*)&v[1])[j]);
    unsigned hi = pack_bf16(((const float*)&v[2])[j], ((const float*)&v[3])[j]);
    int cu = (tr >> 1) ^ (u & 7);  // (n>>2)&7 == u&7
    int off = n * 64 + cu * 8 + (tr & 1) * 4;
    *(uint2*)&tile[off] = uint2{lo, hi};
  }
  __syncthreads();
#pragma unroll
  for (int s2 = 0; s2 < 2; ++s2) {
    int id = tid + s2 * 256;
    int n = id >> 3, cu = id & 7;
    int cx = cu ^ ((n >> 2) & 7);
    uint4 o = *(const uint4*)&tile[n * 64 + cx * 8];
    *(uint4*)&out[(size_t)(n0 + n) * K + k0 + cu * 8] = o;
  }
}

// ---------------- Router: one wave per token ----------------
__global__ __launch_bounds__(256) void router2(
    const float* __restrict__ x, const float* __restrict__ rwt,
    const float* __restrict__ rb, int* __restrict__ counts,
    int* __restrict__ stok, float* __restrict__ gatel) {
  const int lane = threadIdx.x & 63;
  const int wv = threadIdx.x >> 6;
  const int t = blockIdx.x * 4 + wv;
  const int e = lane & 31, h = lane >> 5;
  const float* xp = x + (size_t)t * D_CONST;
  float s = 0.f;
#pragma unroll 8
  for (int d = h; d < D_CONST; d += 2) s = fmaf(xp[d], rwt[d * 32 + e], s);
  s += __shfl_xor(s, 32);
  s += rb[e];
  float mx = s;
#pragma unroll
  for (int m = 16; m >= 1; m >>= 1) mx = fmaxf(mx, __shfl_xor(mx, m));
  float p = expf(s - mx);
  float sum = p;
#pragma unroll
  for (int m = 16; m >= 1; m >>= 1) sum += __shfl_xor(sum, m);
  float sc = p / sum;
  float a = sc, bb = __shfl_xor(a, 1);
  float hi = fmaxf(a, bb), lo = fminf(a, bb);
  float oh = __shfl_xor(hi, 2), ol = __shfl_xor(lo, 2);
  float gs = fmaxf(fmaxf(hi + oh, hi + lo), oh + ol);
  const int g = e >> 2;
  unsigned keep = 0;
  float gv = gs;
#pragma unroll
  for (int r = 0; r < LG_CONST; ++r) {
    float v = gv;
    int gi = g;
#pragma unroll
    for (int m = 16; m >= 1; m >>= 1) {
      float ov = __shfl_xor(v, m);
      int og = __shfl_xor(gi, m);
      if (ov > v || (ov == v && og < gi)) { v = ov; gi = og; }
    }
    keep |= 1u << gi;
    if (g == gi) gv = -1e30f;
  }
  float cand = ((keep >> g) & 1u) ? sc : -1e30f;
  int sel_e = -1;
  float sel_v = 0.f;
#pragma unroll
  for (int r = 0; r < KSEL; ++r) {
    float v = cand;
    int ei = e;
#pragma unroll
    for (int m = 16; m >= 1; m >>= 1) {
      float ov = __shfl_xor(v, m);
      int oe = __shfl_xor(ei, m);
      if (ov > v || (ov == v && oe < ei)) { v = ov; ei = oe; }
    }
    if (lane == r) { sel_e = ei; sel_v = v; }
    if (e == ei) cand = -1e30f;
  }
  if (lane < KSEL) {
    int pos = atomicAdd(&counts[sel_e], 1);
    stok[sel_e * T_CONST + pos] = t;
    gatel[sel_e * T_CONST + pos] = sel_v;
  }
}

// ---------------- offsets + dense work plans ----------------
// plan entry: (z<<8) | (mblk<<3) | nblk ; shared (z==32) first.
__global__ __launch_bounds__(64) void plan_build(
    const int* __restrict__ counts, int* __restrict__ offsets,
    int* __restrict__ plan_up, int* __restrict__ plan_dn, int* __restrict__ meta) {
  const int lane = threadIdx.x;
  // shared-expert tiles first (K=1024, uniform, longest for down)
  for (int i = lane; i < 128; i += 64) {
    int ent = (E_CONST << 8) | i;  // mb = i>>3, nb = i&7
    plan_up[i] = ent;
    plan_dn[i] = ent;
  }
  int cnt = (lane < E_CONST) ? counts[lane] : 0;
  int incl = cnt;
#pragma unroll
  for (int d = 1; d < 64; d <<= 1) {
    int v = __shfl_up(incl, d);
    if (lane >= d) incl += v;
  }
  if (lane < E_CONST) offsets[lane] = incl - cnt;
  if (lane == E_CONST - 1) offsets[E_CONST] = incl;
  int mbs = (cnt + 127) >> 7;
  int pm = mbs;
#pragma unroll
  for (int d = 1; d < 64; d <<= 1) {
    int v = __shfl_up(pm, d);
    if (lane >= d) pm += v;
  }
  int pmex = pm - mbs;
  if (lane < E_CONST) {
    int ub = 128 + pmex * 4, db = 128 + pmex * 8;
    for (int mb = 0; mb < mbs; ++mb) {
#pragma unroll
      for (int nb = 0; nb < 4; ++nb)
        plan_up[ub + mb * 4 + nb] = (lane << 8) | (mb << 3) | nb;
#pragma unroll
      for (int nb = 0; nb < 8; ++nb)
        plan_dn[db + mb * 8 + nb] = (lane << 8) | (mb << 3) | nb;
    }
  }
  if (lane == E_CONST - 1) {
    meta[0] = 128 + pm * 4;
    meta[1] = 128 + pm * 8;
  }
}

// ---------------- gather tokens into expert-packed Xg ----------------
__global__ __launch_bounds__(256) void gather_x(
    const __hip_bfloat16* __restrict__ xbf, const int* __restrict__ counts,
    const int* __restrict__ offsets, const int* __restrict__ stok,
    const float* __restrict__ gatel, __hip_bfloat16* __restrict__ Xg,
    float* __restrict__ cgate, int* __restrict__ tcnt, int* __restrict__ tslot) {
  int e = blockIdx.x;
  int cnt = counts[e];
  int row = blockIdx.y * 16 + (threadIdx.x >> 4);
  if (row >= cnt) return;
  int seg = threadIdx.x & 15;
  int tok = stok[e * T_CONST + row];
  int dst = offsets[e] + row;
  const uint4* src = (const uint4*)(xbf + (size_t)tok * D_CONST);
  uint4* d = (uint4*)(Xg + (size_t)dst * D_CONST);
#pragma unroll
  for (int i = 0; i < 8; ++i) d[i * 16 + seg] = src[i * 16 + seg];
  if (seg == 0) {
    cgate[dst] = gatel[e * T_CONST + row];
    int sl = atomicAdd(&tcnt[tok], 1);
    tslot[tok * 8 + sl] = dst;
  }
}

// ---------------- Fused up-projection (routed z<32, shared z==32) ----------
// 3-stage ring buffer, BK=32, counted vmcnt(12); dense plan + XCD swizzle.
// launch_bounds (256,2): 128 acc regs + ~104 arch VGPR fits; (256,3) spills.
__global__ __launch_bounds__(256, 2) void up_fused(
    const __hip_bfloat16* __restrict__ Xg, const __hip_bfloat16* __restrict__ xbf,
    const __hip_bfloat16* __restrict__ W1t, const __hip_bfloat16* __restrict__ W2t,
    const __hip_bfloat16* __restrict__ sw1t, const __hip_bfloat16* __restrict__ sw2t,
    const float* __restrict__ b1, const float* __restrict__ b2,
    const float* __restrict__ sb1, const float* __restrict__ sb2,
    const int* __restrict__ counts, const int* __restrict__ offsets,
    const int* __restrict__ plan, const int* __restrict__ meta,
    __hip_bfloat16* __restrict__ He, __hip_bfloat16* __restrict__ Hs) {
  const int nw = meta[0];
  const int bx = blockIdx.x;
  if (bx >= nw) return;
  // bijective XCD swizzle (m204): XCD c gets a contiguous chunk of the dense
  // plan -> same-expert tiles share one XCD's L2.
  const int q = nw >> 3, r = nw & 7, c = bx & 7, sl = bx >> 3;
  const int j = (c < r ? c * (q + 1) : r * (q + 1) + (c - r) * q) + sl;
  const int ent = plan[j];
  const int z = ent >> 8;
  const int m0 = ((ent >> 3) & 31) * 128;
  const int n0 = (ent & 7) * 128;
  const bool SH = (z == E_CONST);
  const int cnt = SH ? T_CONST : counts[z];
  const int base = SH ? 0 : offsets[z];

  const __hip_bfloat16* Ab = SH ? (xbf + (size_t)m0 * D_CONST)
                                : (Xg + (size_t)(base + m0) * D_CONST);
  const __hip_bfloat16* B1 = SH ? (sw1t + (size_t)n0 * D_CONST)
                                : (W1t + ((size_t)z * I_CONST + n0) * D_CONST);
  const __hip_bfloat16* B2 = SH ? (sw2t + (size_t)n0 * D_CONST)
                                : (W2t + ((size_t)z * I_CONST + n0) * D_CONST);

  // 3 stages x 4096 shorts (8KB) per tile => 72 KB total
  __shared__ short As[3 * 4096], Bs1[3 * 4096], Bs2[3 * 4096];

  const int tid = threadIdx.x, lane = tid & 63, wv = tid >> 6;
  const int l15 = lane & 15, quad = lane >> 4;
  const int wm = wv & 1, wn = wv >> 1;
  const int lr = lane >> 2;  // row within 16-row group
  const int lc = lane & 3;   // 16B chunk within row

  const __hip_bfloat16 *aG[2], *b1G[2], *b2G[2];
#pragma unroll
  for (int i = 0; i < 2; ++i) {
    int rr = wv * 32 + i * 16 + lr;
    int kap = lc ^ ((rr >> 1) & 3);  // pre-swizzled global chunk
    aG[i]  = Ab + (size_t)rr * D_CONST + kap * 8;
    b1G[i] = B1 + (size_t)rr * D_CONST + kap * 8;
    b2G[i] = B2 + (size_t)rr * D_CONST + kap * 8;
  }
  const int ldsu = wv * 1024 + lane * 8;  // shorts within a stage

  floatx4 acc1[4][4] = {};
  floatx4 acc2[4][4] = {};

  const int nIter = D_CONST / BK;  // 32

  auto stage = [&](int slot, int kk) {
    const int sb = slot * 4096;
#pragma unroll
    for (int i = 0; i < 2; ++i) {
      gload16(aG[i] + kk,  &As [sb + ldsu + i * 512]);
      gload16(b1G[i] + kk, &Bs1[sb + ldsu + i * 512]);
      gload16(b2G[i] + kk, &Bs2[sb + ldsu + i * 512]);
    }
  };

  stage(0, 0);
  stage(1, BK);
  int sl0 = 0, sl1 = 1, sl2 = 2;

  for (int s = 0; s < nIter; ++s) {
    int kn = (s + 2 < nIter) ? (s + 2) * BK : (nIter - 1) * BK;  // clamped
    stage(sl2, kn);
    // wait for stage s (the 12 newer loads stay in flight)
    asm volatile("s_waitcnt vmcnt(12)" ::: "memory");
    __builtin_amdgcn_s_barrier();
    const int sb = sl0 * 4096;
    short8 a[4], x1[4], x2[4];
#pragma unroll
    for (int mi = 0; mi < 4; ++mi) {
      int m = wm * 64 + mi * 16 + l15;
      a[mi] = *(const short8*)&As[sb + m * 32 + (quad ^ ((m >> 1) & 3)) * 8];
    }
#pragma unroll
    for (int ni = 0; ni < 4; ++ni) {
      int n = wn * 64 + ni * 16 + l15;
      int uo = sb + n * 32 + (quad ^ ((n >> 1) & 3)) * 8;
      x1[ni] = *(const short8*)&Bs1[uo];
      x2[ni] = *(const short8*)&Bs2[uo];
    }
    __builtin_amdgcn_s_setprio(1);
#pragma unroll
    for (int mi = 0; mi < 4; ++mi)
#pragma unroll
      for (int ni = 0; ni < 4; ++ni) {
        acc1[mi][ni] = __builtin_amdgcn_mfma_f32_16x16x32_bf16(a[mi], x1[ni], acc1[mi][ni], 0, 0, 0);
        acc2[mi][ni] = __builtin_amdgcn_mfma_f32_16x16x32_bf16(a[mi], x2[ni], acc2[mi][ni], 0, 0, 0);
      }
    __builtin_amdgcn_s_setprio(0);
    __builtin_amdgcn_s_barrier();  // readers done before slot reuse
    int t = sl0; sl0 = sl1; sl1 = sl2; sl2 = t;
  }
  asm volatile("s_waitcnt vmcnt(0)" ::: "memory");  // drain tail DMA

  const float* pb1 = SH ? sb1 : (b1 + (size_t)z * I_CONST);
  const float* pb2 = SH ? sb2 : (b2 + (size_t)z * I_CONST);
  __hip_bfloat16* outp = SH ? (Hs + (size_t)m0 * SI_CONST + n0)
                            : (He + (size_t)(base + m0) * I_CONST + n0);
  const int ldo = SH ? SI_CONST : I_CONST;
  float c1[4], c2[4];
#pragma unroll
  for (int ni = 0; ni < 4; ++ni) {
    int n = wn * 64 + ni * 16 + l15;
    c1[ni] = pb1[n0 + n];
    c2[ni] = pb2[n0 + n];
  }
#pragma unroll
  for (int mi = 0; mi < 4; ++mi) {
#pragma unroll
    for (int reg = 0; reg < 4; ++reg) {
      int m = wm * 64 + mi * 16 + quad * 4 + reg;
      if (m0 + m >= cnt) continue;
#pragma unroll
      for (int ni = 0; ni < 4; ++ni) {
        int n = wn * 64 + ni * 16 + l15;
        float h1 = acc1[mi][ni][reg] + c1[ni];
        float h2 = acc2[mi][ni][reg] + c2[ni];
        float p = h1 * h2;
        float sg = p / (1.f + expf(-p));
        outp[(size_t)m * ldo + n] = __float2bfloat16(sg);
      }
    }
  }
}

// ---------------- Fused down-projection (atomic-free) ----------------
// 3-stage ring, counted vmcnt(8). No XCD swizzle: front-loaded shared tiles
// (2x work) would pile onto 2 XCDs.
// launch_bounds (256,3): 64 acc + ~84 arch VGPR fits the 170 budget.
__global__ __launch_bounds__(256, 3) void down_fused(
    const __hip_bfloat16* __restrict__ He, const __hip_bfloat16* __restrict__ Hs,
    const __hip_bfloat16* __restrict__ W3t, const __hip_bfloat16* __restrict__ sw3t,
    const float* __restrict__ b3, const float* __restrict__ sb3,
    const int* __restrict__ counts, const int* __restrict__ offsets,
    const float* __restrict__ cgate, const int* __restrict__ plan,
    const int* __restrict__ meta, float* __restrict__ Yp, float* __restrict__ out) {
  if ((int)blockIdx.x >= meta[1]) return;
  const int ent = plan[blockIdx.x];
  const int z = ent >> 8;
  const int m0 = ((ent >> 3) & 31) * 128;
  const int n0 = (ent & 7) * 128;  // N = 1024 both paths
  const bool SH = (z == E_CONST);
  const int cnt = SH ? T_CONST : counts[z];
  const int base = SH ? 0 : offsets[z];
  const int Kd = SH ? SI_CONST : I_CONST;

  const __hip_bfloat16* Ab = SH ? (Hs + (size_t)m0 * SI_CONST)
                                : (He + (size_t)(base + m0) * I_CONST);
  const __hip_bfloat16* Bb = SH ? (sw3t + (size_t)n0 * SI_CONST)
                                : (W3t + ((size_t)z * D_CONST + n0) * I_CONST);

  __shared__ short As[3 * 4096], Bs[3 * 4096];  // 48 KB

  const int tid = threadIdx.x, lane = tid & 63, wv = tid >> 6;
  const int l15 = lane & 15, quad = lane >> 4;
  const int wm = wv & 1, wn = wv >> 1;
  const int lr = lane >> 2, lc = lane & 3;

  const __hip_bfloat16 *aG[2], *bG[2];
#pragma unroll
  for (int i = 0; i < 2; ++i) {
    int rr = wv * 32 + i * 16 + lr;
    int kap = lc ^ ((rr >> 1) & 3);
    aG[i] = Ab + (size_t)rr * Kd + kap * 8;
    bG[i] = Bb + (size_t)rr * Kd + kap * 8;
  }
  const int ldsu = wv * 1024 + lane * 8;

  floatx4 acc[4][4] = {};
  const int nIter = Kd / BK;  // 16 routed, 32 shared

  auto stage = [&](int slot, int kk) {
    const int sb = slot * 4096;
#pragma unroll
    for (int i = 0; i < 2; ++i) {
      gload16(aG[i] + kk, &As[sb + ldsu + i * 512]);
      gload16(bG[i] + kk, &Bs[sb + ldsu + i * 512]);
    }
  };

  stage(0, 0);
  stage(1, BK);
  int sl0 = 0, sl1 = 1, sl2 = 2;

  for (int s = 0; s < nIter; ++s) {
    int kn = (s + 2 < nIter) ? (s + 2) * BK : (nIter - 1) * BK;
    stage(sl2, kn);
    asm volatile("s_waitcnt vmcnt(8)" ::: "memory");
    __builtin_amdgcn_s_barrier();
    const int sb = sl0 * 4096;
    short8 a[4], bbf[4];
#pragma unroll
    for (int mi = 0; mi < 4; ++mi) {
      int m = wm * 64 + mi * 16 + l15;
      a[mi] = *(const short8*)&As[sb + m * 32 + (quad ^ ((m >> 1) & 3)) * 8];
    }
#pragma unroll
    for (int ni = 0; ni < 4; ++ni) {
      int n = wn * 64 + ni * 16 + l15;
      bbf[ni] = *(const short8*)&Bs[sb + n * 32 + (quad ^ ((n >> 1) & 3)) * 8];
    }
    __builtin_amdgcn_s_setprio(1);
#pragma unroll
    for (int mi = 0; mi < 4; ++mi)
#pragma unroll
      for (int ni = 0; ni < 4; ++ni)
        acc[mi][ni] = __builtin_amdgcn_mfma_f32_16x16x32_bf16(a[mi], bbf[ni], acc[mi][ni], 0, 0, 0);
    __builtin_amdgcn_s_setprio(0);
    __builtin_amdgcn_s_barrier();
    int t = sl0; sl0 = sl1; sl1 = sl2; sl2 = t;
  }
  asm volatile("s_waitcnt vmcnt(0)" ::: "memory");

  float bias[4];
#pragma unroll
  for (int ni = 0; ni < 4; ++ni) {
    int n = n0 + wn * 64 + ni * 16 + l15;
    bias[ni] = SH ? sb3[n] : b3[(size_t)z * D_CONST + n];
  }
#pragma unroll
  for (int mi = 0; mi < 4; ++mi) {
#pragma unroll
    for (int reg = 0; reg < 4; ++reg) {
      int m = wm * 64 + mi * 16 + quad * 4 + reg;
      if (m0 + m >= cnt) continue;
#pragma unroll
      for (int ni = 0; ni < 4; ++ni) {
        int n = n0 + wn * 64 + ni * 16 + l15;
        float v = acc[mi][ni][reg] + bias[ni];
        if (SH) {
          out[(size_t)(m0 + m) * D_CONST + n] = v;
        } else {
          int grow = base + m0 + m;
          Yp[(size_t)grow * D_CONST + n] = cgate[grow] * v;
        }
      }
    }
  }
}

// ---------------- combine: out[t] = shared(out[t]) + sum_k Yp[tslot[t][k]] ----
__global__ __launch_bounds__(256) void combine(
    const float* __restrict__ Yp, const int* __restrict__ tslot,
    float* __restrict__ out) {
  const int t = blockIdx.x;
  const int d = threadIdx.x * 4;
  const int* ts = &tslot[t * 8];
  float4 o = *(const float4*)&out[(size_t)t * D_CONST + d];
#pragma unroll
  for (int k = 0; k < KSEL; ++k) {
    float4 y = *(const float4*)&Yp[(size_t)ts[k] * D_CONST + d];
    o.x += y.x; o.y += y.y; o.z += y.z; o.w += y.w;
  }
  *(float4*)&out[(size_t)t * D_CONST + d] = o;
}

extern "C" void kernel_launch(void* const* d_in, const int* in_sizes, int n_in,
                              void* d_out, int out_size, void* d_ws, size_t ws_size,
                              hipStream_t stream) {
  const float* x   = (const float*)d_in[0];
  const float* rw  = (const float*)d_in[1];
  const float* rb  = (const float*)d_in[2];
  const float* W1  = (const float*)d_in[3];
  const float* b1  = (const float*)d_in[4];
  const float* W2  = (const float*)d_in[5];
  const float* b2  = (const float*)d_in[6];
  const float* W3  = (const float*)d_in[7];
  const float* b3  = (const float*)d_in[8];
  const float* sw1 = (const float*)d_in[9];
  const float* sb1 = (const float*)d_in[10];
  const float* sw2 = (const float*)d_in[11];
  const float* sb2 = (const float*)d_in[12];
  const float* sw3 = (const float*)d_in[13];
  const float* sb3 = (const float*)d_in[14];
  float* out = (float*)d_out;

  char* w = (char*)d_ws;
  size_t off = 0;
  auto alloc = [&](size_t bytes) {
    char* p = w + off;
    off += (bytes + 255) & ~(size_t)255;
    return p;
  };
  int* counts = (int*)alloc(E_CONST * 4);
  int* offsets = (int*)alloc((E_CONST + 1) * 4);
  int* meta = (int*)alloc(16);
  int* plan_up = (int*)alloc(768 * 4);
  int* plan_dn = (int*)alloc(1280 * 4);
  int* tcnt = (int*)alloc((size_t)T_CONST * 4);
  int* tslot = (int*)alloc((size_t)T_CONST * 8 * 4);
  int* stok = (int*)alloc((size_t)E_CONST * T_CONST * 4);
  float* gatel = (float*)alloc((size_t)E_CONST * T_CONST * 4);
  float* rwt = (float*)alloc((size_t)D_CONST * E_CONST * 4);
  float* cgate = (float*)alloc((size_t)T_CONST * KSEL * 4);
  __hip_bfloat16* x_bf = (__hip_bfloat16*)alloc((size_t)T_CONST * D_CONST * 2);
  __hip_bfloat16* Xg = (__hip_bfloat16*)alloc((size_t)(T_CONST * KSEL + 128) * D_CONST * 2);
  __hip_bfloat16* W1t = (__hip_bfloat16*)alloc((size_t)E_CONST * D_CONST * I_CONST * 2);
  __hip_bfloat16* W2t = (__hip_bfloat16*)alloc((size_t)E_CONST * D_CONST * I_CONST * 2);
  __hip_bfloat16* W3t = (__hip_bfloat16*)alloc((size_t)E_CONST * I_CONST * D_CONST * 2);
  __hip_bfloat16* sw1t = (__hip_bfloat16*)alloc((size_t)D_CONST * SI_CONST * 2);
  __hip_bfloat16* sw2t = (__hip_bfloat16*)alloc((size_t)D_CONST * SI_CONST * 2);
  __hip_bfloat16* sw3t = (__hip_bfloat16*)alloc((size_t)SI_CONST * D_CONST * 2);
  __hip_bfloat16* He = (__hip_bfloat16*)alloc((size_t)(T_CONST * KSEL + 128) * I_CONST * 2);
  __hip_bfloat16* Hs = (__hip_bfloat16*)alloc((size_t)T_CONST * SI_CONST * 2);
  // Yp (routed fp32 partials, 12288x1024x4B = 50.3 MB) aliases W1t+W2t (64 MB),
  // which are dead once up_fused completes. Same-stream ordering guarantees safety.
  float* Yp = (float*)W1t;

  hipMemsetAsync(counts, 0, E_CONST * sizeof(int), stream);
  hipMemsetAsync(tcnt, 0, (size_t)T_CONST * sizeof(int), stream);
  cvt_rwt<<<(D_CONST * E_CONST) / 256, 256, 0, stream>>>(rw, rwt);
  cvt_x<<<(T_CONST * D_CONST) / 1024, 256, 0, stream>>>(x, x_bf);
  transpose_all<<<13056, 256, 0, stream>>>(W1, W2, W3, sw1, sw2, sw3,
                                           W1t, W2t, W3t, sw1t, sw2t, sw3t);
  router2<<<T_CONST / 4, 256, 0, stream>>>(x, rwt, rb, counts, stok, gatel);
  plan_build<<<1, 64, 0, stream>>>(counts, offsets, plan_up, plan_dn, meta);
  gather_x<<<dim3(E_CONST, T_CONST / 16), 256, 0, stream>>>(
      x_bf, counts, offsets, stok, gatel, Xg, cgate, tcnt, tslot);
  up_fused<<<768, 256, 0, stream>>>(
      Xg, x_bf, W1t, W2t, sw1t, sw2t, b1, b2, sb1, sb2, counts, offsets,
      plan_up, meta, He, Hs);
  down_fused<<<1280, 256, 0, stream>>>(
      He, Hs, W3t, sw3t, b3, sb3, counts, offsets, cgate, plan_dn, meta, Yp, out);
  combine<<<T_CONST, 256, 0, stream>>>(Yp, tslot, out);
}

// Round 5
// 459.448 us; speedup vs baseline: 1.0307x; 1.0307x over previous
//
#include <hip/hip_runtime.h>
#include <hip/hip_bf16.h>
#include <math.h>

#define T_CONST 2048
#define D_CONST 1024
#define I_CONST 512
#define SI_CONST 1024
#define E_CONST 32
#define G_CONST 8
#define LG_CONST 4
#define KSEL 6
#define BK 32

typedef __attribute__((ext_vector_type(8))) short short8;
typedef __attribute__((ext_vector_type(4))) float floatx4;

__device__ inline unsigned pack_bf16(float a, float b) {
  __hip_bfloat162 h = __float22bfloat162_rn(float2{a, b});
  return *reinterpret_cast<unsigned*>(&h);
}

// async global->LDS, 16B per lane; LDS dest must be base + lane*16.
__device__ inline void gload16(const void* g, void* l) {
  __builtin_amdgcn_global_load_lds(
      (const __attribute__((address_space(1))) unsigned int*)g,
      (__attribute__((address_space(3))) unsigned int*)l, 16, 0, 0);
}

// ---------------- prep: weight transpose + x/rwt conversion, one launch ----
// Transpose tiles: 64 n-cols x 256 k-rows. Reads 256B segments, writes 512B
// segments. LDS [64][256] bf16 with 5-bit XOR swizzle:
//   cx = chunk ^ ((n>>2)&7) ^ ((n&3)<<3)   (chunk = k/8)
// write phase 2-way aliasing (free), read phase conflict-free.
__global__ __launch_bounds__(256) void prep_all(
    const float* __restrict__ x, const float* __restrict__ rw,
    const float* __restrict__ W1, const float* __restrict__ W2,
    const float* __restrict__ W3, const float* __restrict__ sw1,
    const float* __restrict__ sw2, const float* __restrict__ sw3,
    __hip_bfloat16* __restrict__ x_bf, float* __restrict__ rwt,
    __hip_bfloat16* __restrict__ W1t, __hip_bfloat16* __restrict__ W2t,
    __hip_bfloat16* __restrict__ W3t, __hip_bfloat16* __restrict__ sw1t,
    __hip_bfloat16* __restrict__ sw2t, __hip_bfloat16* __restrict__ sw3t) {
  const int b = blockIdx.x;
  const int tid = threadIdx.x;
  if (b >= 3264) {
    int lb = b - 3264;
    if (lb < 512) {  // cvt_x: 512 blocks x 4096 floats
      size_t base = (size_t)lb * 4096 + tid * 4;
#pragma unroll
      for (int it = 0; it < 4; ++it) {
        float4 v = *(const float4*)&x[base + it * 1024];
        uint2 u{pack_bf16(v.x, v.y), pack_bf16(v.z, v.w)};
        *(uint2*)&x_bf[base + it * 1024] = u;
      }
    } else {  // cvt_rwt: 32 blocks x 1024 elems
      int lb2 = lb - 512;
#pragma unroll
      for (int it = 0; it < 4; ++it) {
        int i = lb2 * 1024 + it * 256 + tid;
        int d = i >> 5, e = i & 31;
        rwt[d * 32 + e] = rw[e * D_CONST + d];
      }
    }
    return;
  }
  const float* in;
  __hip_bfloat16* out;
  int K, N, k0, n0;
  if (b < 2048) {  // W1 / W2: 32 tiles per matrix (4 kb x 8 nb)
    int mat = b >> 5, rem = b & 31;
    K = 1024; N = 512;
    int e = mat & 31;
    in = ((mat < 32) ? W1 : W2) + (size_t)e * (1024 * 512);
    out = ((mat < 32) ? W1t : W2t) + (size_t)e * (1024 * 512);
    k0 = (rem >> 3) * 256; n0 = (rem & 7) * 64;
  } else if (b < 3072) {  // W3: K=512, N=1024 (2 kb x 16 nb)
    int local = b - 2048;
    int e = local >> 5, rem = local & 31;
    K = 512; N = 1024;
    in = W3 + (size_t)e * (512 * 1024);
    out = W3t + (size_t)e * (512 * 1024);
    k0 = (rem >> 4) * 256; n0 = (rem & 15) * 64;
  } else {  // sw1/sw2/sw3: 1024x1024 (4 kb x 16 nb)
    int local = b - 3072;
    int which = local >> 6, rem = local & 63;
    K = 1024; N = 1024;
    in = which == 0 ? sw1 : which == 1 ? sw2 : sw3;
    out = which == 0 ? sw1t : which == 1 ? sw2t : sw3t;
    k0 = (rem >> 4) * 256; n0 = (rem & 15) * 64;
  }
  __shared__ short tile[64 * 256];  // 32 KB
  const int u = tid & 15, tr = tid >> 4;
#pragma unroll
  for (int sub = 0; sub < 4; ++sub) {
    float4 v[4];
#pragma unroll
    for (int r = 0; r < 4; ++r)
      v[r] = *(const float4*)&in[(size_t)(k0 + sub * 64 + 4 * tr + r) * N + n0 + 4 * u];
    int kb = sub * 64 + 4 * tr;
    int chunk = kb >> 3, half = (kb >> 2) & 1;
#pragma unroll
    for (int j = 0; j < 4; ++j) {
      int n = 4 * u + j;
      unsigned lo = pack_bf16(((const float*)&v[0])[j], ((const float*)&v[1])[j]);
      unsigned hi = pack_bf16(((const float*)&v[2])[j], ((const float*)&v[3])[j]);
      int cx = chunk ^ ((n >> 2) & 7) ^ ((n & 3) << 3);
      *(uint2*)&tile[n * 256 + cx * 8 + half * 4] = uint2{lo, hi};
    }
  }
  __syncthreads();
  const int n_ = tid >> 5, c_ = tid & 31;
#pragma unroll
  for (int p = 0; p < 8; ++p) {
    int n = p * 8 + n_;
    int cx = c_ ^ ((n >> 2) & 7) ^ ((n & 3) << 3);
    uint4 o = *(const uint4*)&tile[n * 256 + cx * 8];
    *(uint4*)&out[(size_t)(n0 + n) * K + k0 + c_ * 8] = o;
  }
}

// ---------------- Router: one wave per token ----------------
__global__ __launch_bounds__(256) void router2(
    const float* __restrict__ x, const float* __restrict__ rwt,
    const float* __restrict__ rb, int* __restrict__ counts,
    int* __restrict__ stok, float* __restrict__ gatel) {
  const int lane = threadIdx.x & 63;
  const int wv = threadIdx.x >> 6;
  const int t = blockIdx.x * 4 + wv;
  const int e = lane & 31, h = lane >> 5;
  const float* xp = x + (size_t)t * D_CONST;
  float s = 0.f;
#pragma unroll 8
  for (int d = h; d < D_CONST; d += 2) s = fmaf(xp[d], rwt[d * 32 + e], s);
  s += __shfl_xor(s, 32);
  s += rb[e];
  float mx = s;
#pragma unroll
  for (int m = 16; m >= 1; m >>= 1) mx = fmaxf(mx, __shfl_xor(mx, m));
  float p = expf(s - mx);
  float sum = p;
#pragma unroll
  for (int m = 16; m >= 1; m >>= 1) sum += __shfl_xor(sum, m);
  float sc = p / sum;
  float a = sc, bb = __shfl_xor(a, 1);
  float hi = fmaxf(a, bb), lo = fminf(a, bb);
  float oh = __shfl_xor(hi, 2), ol = __shfl_xor(lo, 2);
  float gs = fmaxf(fmaxf(hi + oh, hi + lo), oh + ol);
  const int g = e >> 2;
  unsigned keep = 0;
  float gv = gs;
#pragma unroll
  for (int r = 0; r < LG_CONST; ++r) {
    float v = gv;
    int gi = g;
#pragma unroll
    for (int m = 16; m >= 1; m >>= 1) {
      float ov = __shfl_xor(v, m);
      int og = __shfl_xor(gi, m);
      if (ov > v || (ov == v && og < gi)) { v = ov; gi = og; }
    }
    keep |= 1u << gi;
    if (g == gi) gv = -1e30f;
  }
  float cand = ((keep >> g) & 1u) ? sc : -1e30f;
  int sel_e = -1;
  float sel_v = 0.f;
#pragma unroll
  for (int r = 0; r < KSEL; ++r) {
    float v = cand;
    int ei = e;
#pragma unroll
    for (int m = 16; m >= 1; m >>= 1) {
      float ov = __shfl_xor(v, m);
      int oe = __shfl_xor(ei, m);
      if (ov > v || (ov == v && oe < ei)) { v = ov; ei = oe; }
    }
    if (lane == r) { sel_e = ei; sel_v = v; }
    if (e == ei) cand = -1e30f;
  }
  if (lane < KSEL) {
    int pos = atomicAdd(&counts[sel_e], 1);
    stok[sel_e * T_CONST + pos] = t;
    gatel[sel_e * T_CONST + pos] = sel_v;
  }
}

// ---------------- offsets + dense work plans ----------------
// plan entry: (z<<8) | (mblk<<3) | nblk ; shared (z==32) first.
__global__ __launch_bounds__(64) void plan_build(
    const int* __restrict__ counts, int* __restrict__ offsets,
    int* __restrict__ plan_up, int* __restrict__ plan_dn, int* __restrict__ meta) {
  const int lane = threadIdx.x;
  for (int i = lane; i < 128; i += 64) {
    int ent = (E_CONST << 8) | i;  // mb = i>>3, nb = i&7
    plan_up[i] = ent;
    plan_dn[i] = ent;
  }
  int cnt = (lane < E_CONST) ? counts[lane] : 0;
  int incl = cnt;
#pragma unroll
  for (int d = 1; d < 64; d <<= 1) {
    int v = __shfl_up(incl, d);
    if (lane >= d) incl += v;
  }
  if (lane < E_CONST) offsets[lane] = incl - cnt;
  if (lane == E_CONST - 1) offsets[E_CONST] = incl;
  int mbs = (cnt + 127) >> 7;
  int pm = mbs;
#pragma unroll
  for (int d = 1; d < 64; d <<= 1) {
    int v = __shfl_up(pm, d);
    if (lane >= d) pm += v;
  }
  int pmex = pm - mbs;
  if (lane < E_CONST) {
    int ub = 128 + pmex * 4, db = 128 + pmex * 8;
    for (int mb = 0; mb < mbs; ++mb) {
#pragma unroll
      for (int nb = 0; nb < 4; ++nb)
        plan_up[ub + mb * 4 + nb] = (lane << 8) | (mb << 3) | nb;
#pragma unroll
      for (int nb = 0; nb < 8; ++nb)
        plan_dn[db + mb * 8 + nb] = (lane << 8) | (mb << 3) | nb;
    }
  }
  if (lane == E_CONST - 1) {
    meta[0] = 128 + pm * 4;
    meta[1] = 128 + pm * 8;
  }
}

// ---------------- gather tokens into expert-packed Xg ----------------
__global__ __launch_bounds__(256) void gather_x(
    const __hip_bfloat16* __restrict__ xbf, const int* __restrict__ counts,
    const int* __restrict__ offsets, const int* __restrict__ stok,
    const float* __restrict__ gatel, __hip_bfloat16* __restrict__ Xg,
    float* __restrict__ cgate, int* __restrict__ tcnt, int* __restrict__ tslot) {
  int e = blockIdx.x;
  int cnt = counts[e];
  int row = blockIdx.y * 16 + (threadIdx.x >> 4);
  if (row >= cnt) return;
  int seg = threadIdx.x & 15;
  int tok = stok[e * T_CONST + row];
  int dst = offsets[e] + row;
  const uint4* src = (const uint4*)(xbf + (size_t)tok * D_CONST);
  uint4* d = (uint4*)(Xg + (size_t)dst * D_CONST);
#pragma unroll
  for (int i = 0; i < 8; ++i) d[i * 16 + seg] = src[i * 16 + seg];
  if (seg == 0) {
    cgate[dst] = gatel[e * T_CONST + row];
    int sl = atomicAdd(&tcnt[tok], 1);
    tslot[tok * 8 + sl] = dst;
  }
}

// ---------------- Fused up-projection (routed z<32, shared z==32) ----------
// 3-stage ring buffer, BK=32, counted vmcnt(12); dense plan + XCD swizzle.
// launch_bounds (256,2): 128 acc regs + ~104 arch VGPR fits; (256,3) spills.
__global__ __launch_bounds__(256, 2) void up_fused(
    const __hip_bfloat16* __restrict__ Xg, const __hip_bfloat16* __restrict__ xbf,
    const __hip_bfloat16* __restrict__ W1t, const __hip_bfloat16* __restrict__ W2t,
    const __hip_bfloat16* __restrict__ sw1t, const __hip_bfloat16* __restrict__ sw2t,
    const float* __restrict__ b1, const float* __restrict__ b2,
    const float* __restrict__ sb1, const float* __restrict__ sb2,
    const int* __restrict__ counts, const int* __restrict__ offsets,
    const int* __restrict__ plan, const int* __restrict__ meta,
    __hip_bfloat16* __restrict__ He, __hip_bfloat16* __restrict__ Hs) {
  const int nw = meta[0];
  const int bx = blockIdx.x;
  if (bx >= nw) return;
  const int q = nw >> 3, r = nw & 7, c = bx & 7, sl = bx >> 3;
  const int j = (c < r ? c * (q + 1) : r * (q + 1) + (c - r) * q) + sl;
  const int ent = plan[j];
  const int z = ent >> 8;
  const int m0 = ((ent >> 3) & 31) * 128;
  const int n0 = (ent & 7) * 128;
  const bool SH = (z == E_CONST);
  const int cnt = SH ? T_CONST : counts[z];
  const int base = SH ? 0 : offsets[z];

  const __hip_bfloat16* Ab = SH ? (xbf + (size_t)m0 * D_CONST)
                                : (Xg + (size_t)(base + m0) * D_CONST);
  const __hip_bfloat16* B1 = SH ? (sw1t + (size_t)n0 * D_CONST)
                                : (W1t + ((size_t)z * I_CONST + n0) * D_CONST);
  const __hip_bfloat16* B2 = SH ? (sw2t + (size_t)n0 * D_CONST)
                                : (W2t + ((size_t)z * I_CONST + n0) * D_CONST);

  __shared__ short As[3 * 4096], Bs1[3 * 4096], Bs2[3 * 4096];

  const int tid = threadIdx.x, lane = tid & 63, wv = tid >> 6;
  const int l15 = lane & 15, quad = lane >> 4;
  const int wm = wv & 1, wn = wv >> 1;
  const int lr = lane >> 2;
  const int lc = lane & 3;

  const __hip_bfloat16 *aG[2], *b1G[2], *b2G[2];
#pragma unroll
  for (int i = 0; i < 2; ++i) {
    int rr = wv * 32 + i * 16 + lr;
    int kap = lc ^ ((rr >> 1) & 3);
    aG[i]  = Ab + (size_t)rr * D_CONST + kap * 8;
    b1G[i] = B1 + (size_t)rr * D_CONST + kap * 8;
    b2G[i] = B2 + (size_t)rr * D_CONST + kap * 8;
  }
  const int ldsu = wv * 1024 + lane * 8;

  floatx4 acc1[4][4] = {};
  floatx4 acc2[4][4] = {};

  const int nIter = D_CONST / BK;  // 32

  auto stage = [&](int slot, int kk) {
    const int sb = slot * 4096;
#pragma unroll
    for (int i = 0; i < 2; ++i) {
      gload16(aG[i] + kk,  &As [sb + ldsu + i * 512]);
      gload16(b1G[i] + kk, &Bs1[sb + ldsu + i * 512]);
      gload16(b2G[i] + kk, &Bs2[sb + ldsu + i * 512]);
    }
  };

  stage(0, 0);
  stage(1, BK);
  int sl0 = 0, sl1 = 1, sl2 = 2;

  for (int s = 0; s < nIter; ++s) {
    int kn = (s + 2 < nIter) ? (s + 2) * BK : (nIter - 1) * BK;
    stage(sl2, kn);
    asm volatile("s_waitcnt vmcnt(12)" ::: "memory");
    __builtin_amdgcn_s_barrier();
    const int sb = sl0 * 4096;
    short8 a[4], x1[4], x2[4];
#pragma unroll
    for (int mi = 0; mi < 4; ++mi) {
      int m = wm * 64 + mi * 16 + l15;
      a[mi] = *(const short8*)&As[sb + m * 32 + (quad ^ ((m >> 1) & 3)) * 8];
    }
#pragma unroll
    for (int ni = 0; ni < 4; ++ni) {
      int n = wn * 64 + ni * 16 + l15;
      int uo = sb + n * 32 + (quad ^ ((n >> 1) & 3)) * 8;
      x1[ni] = *(const short8*)&Bs1[uo];
      x2[ni] = *(const short8*)&Bs2[uo];
    }
    __builtin_amdgcn_s_setprio(1);
#pragma unroll
    for (int mi = 0; mi < 4; ++mi)
#pragma unroll
      for (int ni = 0; ni < 4; ++ni) {
        acc1[mi][ni] = __builtin_amdgcn_mfma_f32_16x16x32_bf16(a[mi], x1[ni], acc1[mi][ni], 0, 0, 0);
        acc2[mi][ni] = __builtin_amdgcn_mfma_f32_16x16x32_bf16(a[mi], x2[ni], acc2[mi][ni], 0, 0, 0);
      }
    __builtin_amdgcn_s_setprio(0);
    __builtin_amdgcn_s_barrier();
    int t = sl0; sl0 = sl1; sl1 = sl2; sl2 = t;
  }
  asm volatile("s_waitcnt vmcnt(0)" ::: "memory");

  const float* pb1 = SH ? sb1 : (b1 + (size_t)z * I_CONST);
  const float* pb2 = SH ? sb2 : (b2 + (size_t)z * I_CONST);
  __hip_bfloat16* outp = SH ? (Hs + (size_t)m0 * SI_CONST + n0)
                            : (He + (size_t)(base + m0) * I_CONST + n0);
  const int ldo = SH ? SI_CONST : I_CONST;
  float c1[4], c2[4];
#pragma unroll
  for (int ni = 0; ni < 4; ++ni) {
    int n = wn * 64 + ni * 16 + l15;
    c1[ni] = pb1[n0 + n];
    c2[ni] = pb2[n0 + n];
  }
#pragma unroll
  for (int mi = 0; mi < 4; ++mi) {
#pragma unroll
    for (int reg = 0; reg < 4; ++reg) {
      int m = wm * 64 + mi * 16 + quad * 4 + reg;
      if (m0 + m >= cnt) continue;
#pragma unroll
      for (int ni = 0; ni < 4; ++ni) {
        int n = wn * 64 + ni * 16 + l15;
        float h1 = acc1[mi][ni][reg] + c1[ni];
        float h2 = acc2[mi][ni][reg] + c2[ni];
        float p = h1 * h2;
        float sg = p / (1.f + expf(-p));
        outp[(size_t)m * ldo + n] = __float2bfloat16(sg);
      }
    }
  }
}

// ---------------- Fused down-projection (atomic-free) ----------------
// 2-stage double buffer (3-stage measured slower, R4), counted vmcnt(4).
// launch_bounds (256,3): 64 acc + ~84 arch VGPR fits the 170 budget.
__global__ __launch_bounds__(256, 3) void down_fused(
    const __hip_bfloat16* __restrict__ He, const __hip_bfloat16* __restrict__ Hs,
    const __hip_bfloat16* __restrict__ W3t, const __hip_bfloat16* __restrict__ sw3t,
    const float* __restrict__ b3, const float* __restrict__ sb3,
    const int* __restrict__ counts, const int* __restrict__ offsets,
    const float* __restrict__ cgate, const int* __restrict__ plan,
    const int* __restrict__ meta, float* __restrict__ Yp, float* __restrict__ out) {
  if ((int)blockIdx.x >= meta[1]) return;
  const int ent = plan[blockIdx.x];
  const int z = ent >> 8;
  const int m0 = ((ent >> 3) & 31) * 128;
  const int n0 = (ent & 7) * 128;
  const bool SH = (z == E_CONST);
  const int cnt = SH ? T_CONST : counts[z];
  const int base = SH ? 0 : offsets[z];
  const int Kd = SH ? SI_CONST : I_CONST;

  const __hip_bfloat16* Ab = SH ? (Hs + (size_t)m0 * SI_CONST)
                                : (He + (size_t)(base + m0) * I_CONST);
  const __hip_bfloat16* Bb = SH ? (sw3t + (size_t)n0 * SI_CONST)
                                : (W3t + ((size_t)z * D_CONST + n0) * I_CONST);

  __shared__ short As[2 * 4096], Bs[2 * 4096];  // 32 KB

  const int tid = threadIdx.x, lane = tid & 63, wv = tid >> 6;
  const int l15 = lane & 15, quad = lane >> 4;
  const int wm = wv & 1, wn = wv >> 1;
  const int lr = lane >> 2, lc = lane & 3;

  const __hip_bfloat16 *aG[2], *bG[2];
#pragma unroll
  for (int i = 0; i < 2; ++i) {
    int rr = wv * 32 + i * 16 + lr;
    int kap = lc ^ ((rr >> 1) & 3);
    aG[i] = Ab + (size_t)rr * Kd + kap * 8;
    bG[i] = Bb + (size_t)rr * Kd + kap * 8;
  }
  const int ldsu = wv * 1024 + lane * 8;

  floatx4 acc[4][4] = {};
  const int nIter = Kd / BK;  // 16 routed, 32 shared

  auto stage = [&](int slot, int kk) {
    const int sb = slot * 4096;
#pragma unroll
    for (int i = 0; i < 2; ++i) {
      gload16(aG[i] + kk, &As[sb + ldsu + i * 512]);
      gload16(bG[i] + kk, &Bs[sb + ldsu + i * 512]);
    }
  };

  stage(0, 0);
  int cur = 0;

  for (int s = 0; s < nIter; ++s) {
    int kn = (s + 1 < nIter) ? (s + 1) * BK : s * BK;
    stage(cur ^ 1, kn);
    asm volatile("s_waitcnt vmcnt(4)" ::: "memory");
    __builtin_amdgcn_s_barrier();
    const int sb = cur * 4096;
    short8 a[4], bbf[4];
#pragma unroll
    for (int mi = 0; mi < 4; ++mi) {
      int m = wm * 64 + mi * 16 + l15;
      a[mi] = *(const short8*)&As[sb + m * 32 + (quad ^ ((m >> 1) & 3)) * 8];
    }
#pragma unroll
    for (int ni = 0; ni < 4; ++ni) {
      int n = wn * 64 + ni * 16 + l15;
      bbf[ni] = *(const short8*)&Bs[sb + n * 32 + (quad ^ ((n >> 1) & 3)) * 8];
    }
    __builtin_amdgcn_s_setprio(1);
#pragma unroll
    for (int mi = 0; mi < 4; ++mi)
#pragma unroll
      for (int ni = 0; ni < 4; ++ni)
        acc[mi][ni] = __builtin_amdgcn_mfma_f32_16x16x32_bf16(a[mi], bbf[ni], acc[mi][ni], 0, 0, 0);
    __builtin_amdgcn_s_setprio(0);
    __builtin_amdgcn_s_barrier();
    cur ^= 1;
  }
  asm volatile("s_waitcnt vmcnt(0)" ::: "memory");

  float bias[4];
#pragma unroll
  for (int ni = 0; ni < 4; ++ni) {
    int n = n0 + wn * 64 + ni * 16 + l15;
    bias[ni] = SH ? sb3[n] : b3[(size_t)z * D_CONST + n];
  }
#pragma unroll
  for (int mi = 0; mi < 4; ++mi) {
#pragma unroll
    for (int reg = 0; reg < 4; ++reg) {
      int m = wm * 64 + mi * 16 + quad * 4 + reg;
      if (m0 + m >= cnt) continue;
#pragma unroll
      for (int ni = 0; ni < 4; ++ni) {
        int n = n0 + wn * 64 + ni * 16 + l15;
        float v = acc[mi][ni][reg] + bias[ni];
        if (SH) {
          out[(size_t)(m0 + m) * D_CONST + n] = v;
        } else {
          int grow = base + m0 + m;
          Yp[(size_t)grow * D_CONST + n] = cgate[grow] * v;
        }
      }
    }
  }
}

// ---------------- combine: out[t] = shared(out[t]) + sum_k Yp[tslot[t][k]] ----
__global__ __launch_bounds__(256) void combine(
    const float* __restrict__ Yp, const int* __restrict__ tslot,
    float* __restrict__ out) {
  const int t = blockIdx.x;
  const int d = threadIdx.x * 4;
  const int* ts = &tslot[t * 8];
  float4 o = *(const float4*)&out[(size_t)t * D_CONST + d];
#pragma unroll
  for (int k = 0; k < KSEL; ++k) {
    float4 y = *(const float4*)&Yp[(size_t)ts[k] * D_CONST + d];
    o.x += y.x; o.y += y.y; o.z += y.z; o.w += y.w;
  }
  *(float4*)&out[(size_t)t * D_CONST + d] = o;
}

extern "C" void kernel_launch(void* const* d_in, const int* in_sizes, int n_in,
                              void* d_out, int out_size, void* d_ws, size_t ws_size,
                              hipStream_t stream) {
  const float* x   = (const float*)d_in[0];
  const float* rw  = (const float*)d_in[1];
  const float* rb  = (const float*)d_in[2];
  const float* W1  = (const float*)d_in[3];
  const float* b1  = (const float*)d_in[4];
  const float* W2  = (const float*)d_in[5];
  const float* b2  = (const float*)d_in[6];
  const float* W3  = (const float*)d_in[7];
  const float* b3  = (const float*)d_in[8];
  const float* sw1 = (const float*)d_in[9];
  const float* sb1 = (const float*)d_in[10];
  const float* sw2 = (const float*)d_in[11];
  const float* sb2 = (const float*)d_in[12];
  const float* sw3 = (const float*)d_in[13];
  const float* sb3 = (const float*)d_in[14];
  float* out = (float*)d_out;

  char* w = (char*)d_ws;
  size_t off = 0;
  auto alloc = [&](size_t bytes) {
    char* p = w + off;
    off += (bytes + 255) & ~(size_t)255;
    return p;
  };
  int* counts = (int*)alloc(E_CONST * 4);
  int* offsets = (int*)alloc((E_CONST + 1) * 4);
  int* meta = (int*)alloc(16);
  int* plan_up = (int*)alloc(768 * 4);
  int* plan_dn = (int*)alloc(1280 * 4);
  int* tcnt = (int*)alloc((size_t)T_CONST * 4);
  int* tslot = (int*)alloc((size_t)T_CONST * 8 * 4);
  int* stok = (int*)alloc((size_t)E_CONST * T_CONST * 4);
  float* gatel = (float*)alloc((size_t)E_CONST * T_CONST * 4);
  float* rwt = (float*)alloc((size_t)D_CONST * E_CONST * 4);
  float* cgate = (float*)alloc((size_t)T_CONST * KSEL * 4);
  __hip_bfloat16* x_bf = (__hip_bfloat16*)alloc((size_t)T_CONST * D_CONST * 2);
  __hip_bfloat16* Xg = (__hip_bfloat16*)alloc((size_t)(T_CONST * KSEL + 128) * D_CONST * 2);
  __hip_bfloat16* W1t = (__hip_bfloat16*)alloc((size_t)E_CONST * D_CONST * I_CONST * 2);
  __hip_bfloat16* W2t = (__hip_bfloat16*)alloc((size_t)E_CONST * D_CONST * I_CONST * 2);
  __hip_bfloat16* W3t = (__hip_bfloat16*)alloc((size_t)E_CONST * I_CONST * D_CONST * 2);
  __hip_bfloat16* sw1t = (__hip_bfloat16*)alloc((size_t)D_CONST * SI_CONST * 2);
  __hip_bfloat16* sw2t = (__hip_bfloat16*)alloc((size_t)D_CONST * SI_CONST * 2);
  __hip_bfloat16* sw3t = (__hip_bfloat16*)alloc((size_t)SI_CONST * D_CONST * 2);
  __hip_bfloat16* He = (__hip_bfloat16*)alloc((size_t)(T_CONST * KSEL + 128) * I_CONST * 2);
  __hip_bfloat16* Hs = (__hip_bfloat16*)alloc((size_t)T_CONST * SI_CONST * 2);
  // Yp (routed fp32 partials, 50.3 MB) aliases W1t+W2t (64 MB), dead after up.
  float* Yp = (float*)W1t;

  hipMemsetAsync(counts, 0, E_CONST * sizeof(int), stream);
  hipMemsetAsync(tcnt, 0, (size_t)T_CONST * sizeof(int), stream);
  prep_all<<<3808, 256, 0, stream>>>(x, rw, W1, W2, W3, sw1, sw2, sw3,
                                     x_bf, rwt, W1t, W2t, W3t, sw1t, sw2t, sw3t);
  router2<<<T_CONST / 4, 256, 0, stream>>>(x, rwt, rb, counts, stok, gatel);
  plan_build<<<1, 64, 0, stream>>>(counts, offsets, plan_up, plan_dn, meta);
  gather_x<<<dim3(E_CONST, T_CONST / 16), 256, 0, stream>>>(
      x_bf, counts, offsets, stok, gatel, Xg, cgate, tcnt, tslot);
  up_fused<<<768, 256, 0, stream>>>(
      Xg, x_bf, W1t, W2t, sw1t, sw2t, b1, b2, sb1, sb2, counts, offsets,
      plan_up, meta, He, Hs);
  down_fused<<<1280, 256, 0, stream>>>(
      He, Hs, W3t, sw3t, b3, sb3, counts, offsets, cgate, plan_dn, meta, Yp, out);
  combine<<<T_CONST, 256, 0, stream>>>(Yp, tslot, out);
}

// Round 6
// 448.852 us; speedup vs baseline: 1.0551x; 1.0236x over previous
//
#include <hip/hip_runtime.h>
#include <hip/hip_bf16.h>
#include <math.h>

#define T_CONST 2048
#define D_CONST 1024
#define I_CONST 512
#define SI_CONST 1024
#define E_CONST 32
#define G_CONST 8
#define LG_CONST 4
#define KSEL 6
#define BK 32

typedef __attribute__((ext_vector_type(8))) short short8;
typedef __attribute__((ext_vector_type(4))) float floatx4;

__device__ inline unsigned pack_bf16(float a, float b) {
  __hip_bfloat162 h = __float22bfloat162_rn(float2{a, b});
  return *reinterpret_cast<unsigned*>(&h);
}

// async global->LDS, 16B per lane; LDS dest must be base + lane*16.
__device__ inline void gload16(const void* g, void* l) {
  __builtin_amdgcn_global_load_lds(
      (const __attribute__((address_space(1))) unsigned int*)g,
      (__attribute__((address_space(3))) unsigned int*)l, 16, 0, 0);
}

// ---------------- prep: weight transpose + x/rwt conversion, one launch ----
__global__ __launch_bounds__(256) void prep_all(
    const float* __restrict__ x, const float* __restrict__ rw,
    const float* __restrict__ W1, const float* __restrict__ W2,
    const float* __restrict__ W3, const float* __restrict__ sw1,
    const float* __restrict__ sw2, const float* __restrict__ sw3,
    __hip_bfloat16* __restrict__ x_bf, float* __restrict__ rwt,
    __hip_bfloat16* __restrict__ W1t, __hip_bfloat16* __restrict__ W2t,
    __hip_bfloat16* __restrict__ W3t, __hip_bfloat16* __restrict__ sw1t,
    __hip_bfloat16* __restrict__ sw2t, __hip_bfloat16* __restrict__ sw3t) {
  const int b = blockIdx.x;
  const int tid = threadIdx.x;
  if (b >= 3264) {
    int lb = b - 3264;
    if (lb < 512) {  // cvt_x
      size_t base = (size_t)lb * 4096 + tid * 4;
#pragma unroll
      for (int it = 0; it < 4; ++it) {
        float4 v = *(const float4*)&x[base + it * 1024];
        uint2 u{pack_bf16(v.x, v.y), pack_bf16(v.z, v.w)};
        *(uint2*)&x_bf[base + it * 1024] = u;
      }
    } else {  // cvt_rwt
      int lb2 = lb - 512;
#pragma unroll
      for (int it = 0; it < 4; ++it) {
        int i = lb2 * 1024 + it * 256 + tid;
        int d = i >> 5, e = i & 31;
        rwt[d * 32 + e] = rw[e * D_CONST + d];
      }
    }
    return;
  }
  const float* in;
  __hip_bfloat16* out;
  int K, N, k0, n0;
  if (b < 2048) {  // W1 / W2
    int mat = b >> 5, rem = b & 31;
    K = 1024; N = 512;
    int e = mat & 31;
    in = ((mat < 32) ? W1 : W2) + (size_t)e * (1024 * 512);
    out = ((mat < 32) ? W1t : W2t) + (size_t)e * (1024 * 512);
    k0 = (rem >> 3) * 256; n0 = (rem & 7) * 64;
  } else if (b < 3072) {  // W3
    int local = b - 2048;
    int e = local >> 5, rem = local & 31;
    K = 512; N = 1024;
    in = W3 + (size_t)e * (512 * 1024);
    out = W3t + (size_t)e * (512 * 1024);
    k0 = (rem >> 4) * 256; n0 = (rem & 15) * 64;
  } else {  // sw1/sw2/sw3
    int local = b - 3072;
    int which = local >> 6, rem = local & 63;
    K = 1024; N = 1024;
    in = which == 0 ? sw1 : which == 1 ? sw2 : sw3;
    out = which == 0 ? sw1t : which == 1 ? sw2t : sw3t;
    k0 = (rem >> 4) * 256; n0 = (rem & 15) * 64;
  }
  __shared__ short tile[64 * 256];  // 32 KB
  const int u = tid & 15, tr = tid >> 4;
#pragma unroll
  for (int sub = 0; sub < 4; ++sub) {
    float4 v[4];
#pragma unroll
    for (int r = 0; r < 4; ++r)
      v[r] = *(const float4*)&in[(size_t)(k0 + sub * 64 + 4 * tr + r) * N + n0 + 4 * u];
    int kb = sub * 64 + 4 * tr;
    int chunk = kb >> 3, half = (kb >> 2) & 1;
#pragma unroll
    for (int j = 0; j < 4; ++j) {
      int n = 4 * u + j;
      unsigned lo = pack_bf16(((const float*)&v[0])[j], ((const float*)&v[1])[j]);
      unsigned hi = pack_bf16(((const float*)&v[2])[j], ((const float*)&v[3])[j]);
      int cx = chunk ^ ((n >> 2) & 7) ^ ((n & 3) << 3);
      *(uint2*)&tile[n * 256 + cx * 8 + half * 4] = uint2{lo, hi};
    }
  }
  __syncthreads();
  const int n_ = tid >> 5, c_ = tid & 31;
#pragma unroll
  for (int p = 0; p < 8; ++p) {
    int n = p * 8 + n_;
    int cx = c_ ^ ((n >> 2) & 7) ^ ((n & 3) << 3);
    uint4 o = *(const uint4*)&tile[n * 256 + cx * 8];
    *(uint4*)&out[(size_t)(n0 + n) * K + k0 + c_ * 8] = o;
  }
}

// ---------------- Router: one wave per token ----------------
__global__ __launch_bounds__(256) void router2(
    const float* __restrict__ x, const float* __restrict__ rwt,
    const float* __restrict__ rb, int* __restrict__ counts,
    int* __restrict__ stok, float* __restrict__ gatel) {
  const int lane = threadIdx.x & 63;
  const int wv = threadIdx.x >> 6;
  const int t = blockIdx.x * 4 + wv;
  const int e = lane & 31, h = lane >> 5;
  const float* xp = x + (size_t)t * D_CONST;
  float s = 0.f;
#pragma unroll 8
  for (int d = h; d < D_CONST; d += 2) s = fmaf(xp[d], rwt[d * 32 + e], s);
  s += __shfl_xor(s, 32);
  s += rb[e];
  float mx = s;
#pragma unroll
  for (int m = 16; m >= 1; m >>= 1) mx = fmaxf(mx, __shfl_xor(mx, m));
  float p = expf(s - mx);
  float sum = p;
#pragma unroll
  for (int m = 16; m >= 1; m >>= 1) sum += __shfl_xor(sum, m);
  float sc = p / sum;
  float a = sc, bb = __shfl_xor(a, 1);
  float hi = fmaxf(a, bb), lo = fminf(a, bb);
  float oh = __shfl_xor(hi, 2), ol = __shfl_xor(lo, 2);
  float gs = fmaxf(fmaxf(hi + oh, hi + lo), oh + ol);
  const int g = e >> 2;
  unsigned keep = 0;
  float gv = gs;
#pragma unroll
  for (int r = 0; r < LG_CONST; ++r) {
    float v = gv;
    int gi = g;
#pragma unroll
    for (int m = 16; m >= 1; m >>= 1) {
      float ov = __shfl_xor(v, m);
      int og = __shfl_xor(gi, m);
      if (ov > v || (ov == v && og < gi)) { v = ov; gi = og; }
    }
    keep |= 1u << gi;
    if (g == gi) gv = -1e30f;
  }
  float cand = ((keep >> g) & 1u) ? sc : -1e30f;
  int sel_e = -1;
  float sel_v = 0.f;
#pragma unroll
  for (int r = 0; r < KSEL; ++r) {
    float v = cand;
    int ei = e;
#pragma unroll
    for (int m = 16; m >= 1; m >>= 1) {
      float ov = __shfl_xor(v, m);
      int oe = __shfl_xor(ei, m);
      if (ov > v || (ov == v && oe < ei)) { v = ov; ei = oe; }
    }
    if (lane == r) { sel_e = ei; sel_v = v; }
    if (e == ei) cand = -1e30f;
  }
  if (lane < KSEL) {
    int pos = atomicAdd(&counts[sel_e], 1);
    stok[sel_e * T_CONST + pos] = t;
    gatel[sel_e * T_CONST + pos] = sel_v;
  }
}

// ---------------- offsets + dense work plans ----------------
__global__ __launch_bounds__(64) void plan_build(
    const int* __restrict__ counts, int* __restrict__ offsets,
    int* __restrict__ plan_up, int* __restrict__ plan_dn, int* __restrict__ meta) {
  const int lane = threadIdx.x;
  for (int i = lane; i < 128; i += 64) {
    int ent = (E_CONST << 8) | i;  // mb = i>>3, nb = i&7
    plan_up[i] = ent;
    plan_dn[i] = ent;
  }
  int cnt = (lane < E_CONST) ? counts[lane] : 0;
  int incl = cnt;
#pragma unroll
  for (int d = 1; d < 64; d <<= 1) {
    int v = __shfl_up(incl, d);
    if (lane >= d) incl += v;
  }
  if (lane < E_CONST) offsets[lane] = incl - cnt;
  if (lane == E_CONST - 1) offsets[E_CONST] = incl;
  int mbs = (cnt + 127) >> 7;
  int pm = mbs;
#pragma unroll
  for (int d = 1; d < 64; d <<= 1) {
    int v = __shfl_up(pm, d);
    if (lane >= d) pm += v;
  }
  int pmex = pm - mbs;
  if (lane < E_CONST) {
    int ub = 128 + pmex * 4, db = 128 + pmex * 8;
    for (int mb = 0; mb < mbs; ++mb) {
#pragma unroll
      for (int nb = 0; nb < 4; ++nb)
        plan_up[ub + mb * 4 + nb] = (lane << 8) | (mb << 3) | nb;
#pragma unroll
      for (int nb = 0; nb < 8; ++nb)
        plan_dn[db + mb * 8 + nb] = (lane << 8) | (mb << 3) | nb;
    }
  }
  if (lane == E_CONST - 1) {
    meta[0] = 128 + pm * 4;
    meta[1] = 128 + pm * 8;
  }
}

// ---------------- gather tokens into expert-packed Xg ----------------
__global__ __launch_bounds__(256) void gather_x(
    const __hip_bfloat16* __restrict__ xbf, const int* __restrict__ counts,
    const int* __restrict__ offsets, const int* __restrict__ stok,
    const float* __restrict__ gatel, __hip_bfloat16* __restrict__ Xg,
    float* __restrict__ cgate, int* __restrict__ tcnt, int* __restrict__ tslot) {
  int e = blockIdx.x;
  int cnt = counts[e];
  int row = blockIdx.y * 16 + (threadIdx.x >> 4);
  if (row >= cnt) return;
  int seg = threadIdx.x & 15;
  int tok = stok[e * T_CONST + row];
  int dst = offsets[e] + row;
  const uint4* src = (const uint4*)(xbf + (size_t)tok * D_CONST);
  uint4* d = (uint4*)(Xg + (size_t)dst * D_CONST);
#pragma unroll
  for (int i = 0; i < 8; ++i) d[i * 16 + seg] = src[i * 16 + seg];
  if (seg == 0) {
    cgate[dst] = gatel[e * T_CONST + row];
    int sl = atomicAdd(&tcnt[tok], 1);
    tslot[tok * 8 + sl] = dst;
  }
}

// ---------------- Fused up-projection (routed z<32, shared z==32) ----------
// 512 threads / 8 waves per 128x128 tile; per-wave 64x32 sub-tile -> acc is
// 64 VGPR (2 matmuls x 8 frags). __launch_bounds__(512,4) caps VGPR at 128
// -> 4 waves/SIMD (2 blocks/CU), 2x the TLP of the 256-thread/232-reg config.
// 3-stage ring (72 KB; 2 blocks = 144 <= 160), 1 gload16/thread/matrix,
// counted vmcnt(6). Dense plan + bijective XCD swizzle.
__global__ __launch_bounds__(512, 4) void up_fused(
    const __hip_bfloat16* __restrict__ Xg, const __hip_bfloat16* __restrict__ xbf,
    const __hip_bfloat16* __restrict__ W1t, const __hip_bfloat16* __restrict__ W2t,
    const __hip_bfloat16* __restrict__ sw1t, const __hip_bfloat16* __restrict__ sw2t,
    const float* __restrict__ b1, const float* __restrict__ b2,
    const float* __restrict__ sb1, const float* __restrict__ sb2,
    const int* __restrict__ counts, const int* __restrict__ offsets,
    const int* __restrict__ plan, const int* __restrict__ meta,
    __hip_bfloat16* __restrict__ He, __hip_bfloat16* __restrict__ Hs) {
  const int nw = meta[0];
  const int bx = blockIdx.x;
  if (bx >= nw) return;
  const int q = nw >> 3, r = nw & 7, c = bx & 7, sl = bx >> 3;
  const int j = (c < r ? c * (q + 1) : r * (q + 1) + (c - r) * q) + sl;
  const int ent = plan[j];
  const int z = ent >> 8;
  const int m0 = ((ent >> 3) & 31) * 128;
  const int n0 = (ent & 7) * 128;
  const bool SH = (z == E_CONST);
  const int cnt = SH ? T_CONST : counts[z];
  const int base = SH ? 0 : offsets[z];

  const __hip_bfloat16* Ab = SH ? (xbf + (size_t)m0 * D_CONST)
                                : (Xg + (size_t)(base + m0) * D_CONST);
  const __hip_bfloat16* B1 = SH ? (sw1t + (size_t)n0 * D_CONST)
                                : (W1t + ((size_t)z * I_CONST + n0) * D_CONST);
  const __hip_bfloat16* B2 = SH ? (sw2t + (size_t)n0 * D_CONST)
                                : (W2t + ((size_t)z * I_CONST + n0) * D_CONST);

  __shared__ short As[3 * 4096], Bs1[3 * 4096], Bs2[3 * 4096];  // 72 KB

  const int tid = threadIdx.x, lane = tid & 63, wv = tid >> 6;
  const int l15 = lane & 15, quad = lane >> 4;
  const int wm = wv & 1, wn = wv >> 1;  // 2 x 4 wave grid, 64x32 per wave
  const int srow = tid >> 2;            // staging row 0..127
  const int slc = tid & 3;              // 16B chunk in row
  const int kap = slc ^ ((srow >> 1) & 3);

  const __hip_bfloat16* aG  = Ab + (size_t)srow * D_CONST + kap * 8;
  const __hip_bfloat16* b1G = B1 + (size_t)srow * D_CONST + kap * 8;
  const __hip_bfloat16* b2G = B2 + (size_t)srow * D_CONST + kap * 8;
  const int ldsu = tid * 8;  // shorts within a stage

  floatx4 acc1[4][2] = {};
  floatx4 acc2[4][2] = {};

  const int nIter = D_CONST / BK;  // 32

  auto stage = [&](int slot, int kk) {
    const int sb = slot * 4096;
    gload16(aG + kk,  &As [sb + ldsu]);
    gload16(b1G + kk, &Bs1[sb + ldsu]);
    gload16(b2G + kk, &Bs2[sb + ldsu]);
  };

  stage(0, 0);
  stage(1, BK);
  int sl0 = 0, sl1 = 1, sl2 = 2;

  for (int s = 0; s < nIter; ++s) {
    int kn = (s + 2 < nIter) ? (s + 2) * BK : (nIter - 1) * BK;
    stage(sl2, kn);
    asm volatile("s_waitcnt vmcnt(6)" ::: "memory");
    __builtin_amdgcn_s_barrier();
    const int sb = sl0 * 4096;
    short8 x1[2], x2[2];
#pragma unroll
    for (int ni = 0; ni < 2; ++ni) {
      int n = wn * 32 + ni * 16 + l15;
      int uo = sb + n * 32 + (quad ^ ((n >> 1) & 3)) * 8;
      x1[ni] = *(const short8*)&Bs1[uo];
      x2[ni] = *(const short8*)&Bs2[uo];
    }
    __builtin_amdgcn_s_setprio(1);
#pragma unroll
    for (int mi = 0; mi < 4; ++mi) {
      int m = wm * 64 + mi * 16 + l15;
      short8 a = *(const short8*)&As[sb + m * 32 + (quad ^ ((m >> 1) & 3)) * 8];
#pragma unroll
      for (int ni = 0; ni < 2; ++ni) {
        acc1[mi][ni] = __builtin_amdgcn_mfma_f32_16x16x32_bf16(a, x1[ni], acc1[mi][ni], 0, 0, 0);
        acc2[mi][ni] = __builtin_amdgcn_mfma_f32_16x16x32_bf16(a, x2[ni], acc2[mi][ni], 0, 0, 0);
      }
    }
    __builtin_amdgcn_s_setprio(0);
    __builtin_amdgcn_s_barrier();
    int t = sl0; sl0 = sl1; sl1 = sl2; sl2 = t;
  }
  asm volatile("s_waitcnt vmcnt(0)" ::: "memory");

  const float* pb1 = SH ? sb1 : (b1 + (size_t)z * I_CONST);
  const float* pb2 = SH ? sb2 : (b2 + (size_t)z * I_CONST);
  __hip_bfloat16* outp = SH ? (Hs + (size_t)m0 * SI_CONST + n0)
                            : (He + (size_t)(base + m0) * I_CONST + n0);
  const int ldo = SH ? SI_CONST : I_CONST;
  float c1[2], c2[2];
#pragma unroll
  for (int ni = 0; ni < 2; ++ni) {
    int n = wn * 32 + ni * 16 + l15;
    c1[ni] = pb1[n0 + n];
    c2[ni] = pb2[n0 + n];
  }
#pragma unroll
  for (int mi = 0; mi < 4; ++mi) {
#pragma unroll
    for (int reg = 0; reg < 4; ++reg) {
      int m = wm * 64 + mi * 16 + quad * 4 + reg;
      if (m0 + m >= cnt) continue;
#pragma unroll
      for (int ni = 0; ni < 2; ++ni) {
        int n = wn * 32 + ni * 16 + l15;
        float h1 = acc1[mi][ni][reg] + c1[ni];
        float h2 = acc2[mi][ni][reg] + c2[ni];
        float p = h1 * h2;
        float sg = p / (1.f + expf(-p));
        outp[(size_t)m * ldo + n] = __float2bfloat16(sg);
      }
    }
  }
}

// ---------------- Fused down-projection (atomic-free) ----------------
// Same 8-wave restructure: acc 32 VGPR, (512,4) -> 4 waves/SIMD.
// 2-stage (32 KB), 1 gload16/thread/matrix, vmcnt(2).
__global__ __launch_bounds__(512, 4) void down_fused(
    const __hip_bfloat16* __restrict__ He, const __hip_bfloat16* __restrict__ Hs,
    const __hip_bfloat16* __restrict__ W3t, const __hip_bfloat16* __restrict__ sw3t,
    const float* __restrict__ b3, const float* __restrict__ sb3,
    const int* __restrict__ counts, const int* __restrict__ offsets,
    const float* __restrict__ cgate, const int* __restrict__ plan,
    const int* __restrict__ meta, float* __restrict__ Yp, float* __restrict__ out) {
  if ((int)blockIdx.x >= meta[1]) return;
  const int ent = plan[blockIdx.x];
  const int z = ent >> 8;
  const int m0 = ((ent >> 3) & 31) * 128;
  const int n0 = (ent & 7) * 128;
  const bool SH = (z == E_CONST);
  const int cnt = SH ? T_CONST : counts[z];
  const int base = SH ? 0 : offsets[z];
  const int Kd = SH ? SI_CONST : I_CONST;

  const __hip_bfloat16* Ab = SH ? (Hs + (size_t)m0 * SI_CONST)
                                : (He + (size_t)(base + m0) * I_CONST);
  const __hip_bfloat16* Bb = SH ? (sw3t + (size_t)n0 * SI_CONST)
                                : (W3t + ((size_t)z * D_CONST + n0) * I_CONST);

  __shared__ short As[2 * 4096], Bs[2 * 4096];  // 32 KB

  const int tid = threadIdx.x, lane = tid & 63, wv = tid >> 6;
  const int l15 = lane & 15, quad = lane >> 4;
  const int wm = wv & 1, wn = wv >> 1;
  const int srow = tid >> 2, slc = tid & 3;
  const int kap = slc ^ ((srow >> 1) & 3);

  const __hip_bfloat16* aG = Ab + (size_t)srow * Kd + kap * 8;
  const __hip_bfloat16* bG = Bb + (size_t)srow * Kd + kap * 8;
  const int ldsu = tid * 8;

  floatx4 acc[4][2] = {};
  const int nIter = Kd / BK;  // 16 routed, 32 shared

  auto stage = [&](int slot, int kk) {
    const int sb = slot * 4096;
    gload16(aG + kk, &As[sb + ldsu]);
    gload16(bG + kk, &Bs[sb + ldsu]);
  };

  stage(0, 0);
  int cur = 0;

  for (int s = 0; s < nIter; ++s) {
    int kn = (s + 1 < nIter) ? (s + 1) * BK : s * BK;
    stage(cur ^ 1, kn);
    asm volatile("s_waitcnt vmcnt(2)" ::: "memory");
    __builtin_amdgcn_s_barrier();
    const int sb = cur * 4096;
    short8 bb[2];
#pragma unroll
    for (int ni = 0; ni < 2; ++ni) {
      int n = wn * 32 + ni * 16 + l15;
      bb[ni] = *(const short8*)&Bs[sb + n * 32 + (quad ^ ((n >> 1) & 3)) * 8];
    }
    __builtin_amdgcn_s_setprio(1);
#pragma unroll
    for (int mi = 0; mi < 4; ++mi) {
      int m = wm * 64 + mi * 16 + l15;
      short8 a = *(const short8*)&As[sb + m * 32 + (quad ^ ((m >> 1) & 3)) * 8];
#pragma unroll
      for (int ni = 0; ni < 2; ++ni)
        acc[mi][ni] = __builtin_amdgcn_mfma_f32_16x16x32_bf16(a, bb[ni], acc[mi][ni], 0, 0, 0);
    }
    __builtin_amdgcn_s_setprio(0);
    __builtin_amdgcn_s_barrier();
    cur ^= 1;
  }
  asm volatile("s_waitcnt vmcnt(0)" ::: "memory");

  float bias[2];
#pragma unroll
  for (int ni = 0; ni < 2; ++ni) {
    int n = n0 + wn * 32 + ni * 16 + l15;
    bias[ni] = SH ? sb3[n] : b3[(size_t)z * D_CONST + n];
  }
#pragma unroll
  for (int mi = 0; mi < 4; ++mi) {
#pragma unroll
    for (int reg = 0; reg < 4; ++reg) {
      int m = wm * 64 + mi * 16 + quad * 4 + reg;
      if (m0 + m >= cnt) continue;
#pragma unroll
      for (int ni = 0; ni < 2; ++ni) {
        int n = n0 + wn * 32 + ni * 16 + l15;
        float v = acc[mi][ni][reg] + bias[ni];
        if (SH) {
          out[(size_t)(m0 + m) * D_CONST + n] = v;
        } else {
          int grow = base + m0 + m;
          Yp[(size_t)grow * D_CONST + n] = cgate[grow] * v;
        }
      }
    }
  }
}

// ---------------- combine: out[t] = shared(out[t]) + sum_k Yp[tslot[t][k]] ----
__global__ __launch_bounds__(256) void combine(
    const float* __restrict__ Yp, const int* __restrict__ tslot,
    float* __restrict__ out) {
  const int t = blockIdx.x;
  const int d = threadIdx.x * 4;
  const int* ts = &tslot[t * 8];
  float4 o = *(const float4*)&out[(size_t)t * D_CONST + d];
#pragma unroll
  for (int k = 0; k < KSEL; ++k) {
    float4 y = *(const float4*)&Yp[(size_t)ts[k] * D_CONST + d];
    o.x += y.x; o.y += y.y; o.z += y.z; o.w += y.w;
  }
  *(float4*)&out[(size_t)t * D_CONST + d] = o;
}

extern "C" void kernel_launch(void* const* d_in, const int* in_sizes, int n_in,
                              void* d_out, int out_size, void* d_ws, size_t ws_size,
                              hipStream_t stream) {
  const float* x   = (const float*)d_in[0];
  const float* rw  = (const float*)d_in[1];
  const float* rb  = (const float*)d_in[2];
  const float* W1  = (const float*)d_in[3];
  const float* b1  = (const float*)d_in[4];
  const float* W2  = (const float*)d_in[5];
  const float* b2  = (const float*)d_in[6];
  const float* W3  = (const float*)d_in[7];
  const float* b3  = (const float*)d_in[8];
  const float* sw1 = (const float*)d_in[9];
  const float* sb1 = (const float*)d_in[10];
  const float* sw2 = (const float*)d_in[11];
  const float* sb2 = (const float*)d_in[12];
  const float* sw3 = (const float*)d_in[13];
  const float* sb3 = (const float*)d_in[14];
  float* out = (float*)d_out;

  char* w = (char*)d_ws;
  size_t off = 0;
  auto alloc = [&](size_t bytes) {
    char* p = w + off;
    off += (bytes + 255) & ~(size_t)255;
    return p;
  };
  int* counts = (int*)alloc(E_CONST * 4);
  int* offsets = (int*)alloc((E_CONST + 1) * 4);
  int* meta = (int*)alloc(16);
  int* plan_up = (int*)alloc(768 * 4);
  int* plan_dn = (int*)alloc(1280 * 4);
  int* tcnt = (int*)alloc((size_t)T_CONST * 4);
  int* tslot = (int*)alloc((size_t)T_CONST * 8 * 4);
  int* stok = (int*)alloc((size_t)E_CONST * T_CONST * 4);
  float* gatel = (float*)alloc((size_t)E_CONST * T_CONST * 4);
  float* rwt = (float*)alloc((size_t)D_CONST * E_CONST * 4);
  float* cgate = (float*)alloc((size_t)T_CONST * KSEL * 4);
  __hip_bfloat16* x_bf = (__hip_bfloat16*)alloc((size_t)T_CONST * D_CONST * 2);
  __hip_bfloat16* Xg = (__hip_bfloat16*)alloc((size_t)(T_CONST * KSEL + 128) * D_CONST * 2);
  __hip_bfloat16* W1t = (__hip_bfloat16*)alloc((size_t)E_CONST * D_CONST * I_CONST * 2);
  __hip_bfloat16* W2t = (__hip_bfloat16*)alloc((size_t)E_CONST * D_CONST * I_CONST * 2);
  __hip_bfloat16* W3t = (__hip_bfloat16*)alloc((size_t)E_CONST * I_CONST * D_CONST * 2);
  __hip_bfloat16* sw1t = (__hip_bfloat16*)alloc((size_t)D_CONST * SI_CONST * 2);
  __hip_bfloat16* sw2t = (__hip_bfloat16*)alloc((size_t)D_CONST * SI_CONST * 2);
  __hip_bfloat16* sw3t = (__hip_bfloat16*)alloc((size_t)SI_CONST * D_CONST * 2);
  __hip_bfloat16* He = (__hip_bfloat16*)alloc((size_t)(T_CONST * KSEL + 128) * I_CONST * 2);
  __hip_bfloat16* Hs = (__hip_bfloat16*)alloc((size_t)T_CONST * SI_CONST * 2);
  // Yp (routed fp32 partials, 50.3 MB) aliases W1t+W2t (64 MB), dead after up.
  float* Yp = (float*)W1t;

  hipMemsetAsync(counts, 0, E_CONST * sizeof(int), stream);
  hipMemsetAsync(tcnt, 0, (size_t)T_CONST * sizeof(int), stream);
  prep_all<<<3808, 256, 0, stream>>>(x, rw, W1, W2, W3, sw1, sw2, sw3,
                                     x_bf, rwt, W1t, W2t, W3t, sw1t, sw2t, sw3t);
  router2<<<T_CONST / 4, 256, 0, stream>>>(x, rwt, rb, counts, stok, gatel);
  plan_build<<<1, 64, 0, stream>>>(counts, offsets, plan_up, plan_dn, meta);
  gather_x<<<dim3(E_CONST, T_CONST / 16), 256, 0, stream>>>(
      x_bf, counts, offsets, stok, gatel, Xg, cgate, tcnt, tslot);
  up_fused<<<768, 512, 0, stream>>>(
      Xg, x_bf, W1t, W2t, sw1t, sw2t, b1, b2, sb1, sb2, counts, offsets,
      plan_up, meta, He, Hs);
  down_fused<<<1280, 512, 0, stream>>>(
      He, Hs, W3t, sw3t, b3, sb3, counts, offsets, cgate, plan_dn, meta, Yp, out);
  combine<<<T_CONST, 256, 0, stream>>>(Yp, tslot, out);
}